// Round 7
// baseline (324.609 us; speedup 1.0000x reference)
//
#include <hip/hip_runtime.h>
#include <hip/hip_fp16.h>
#include <math.h>

// GCN 2-layer (DGL GraphConv norm='both'), CSR via rank-atomics:
//   rank[e] = atomicAdd(&in_cnt[dst[e]], 1)    -> in_cnt becomes in_deg
//   row_start = exclusive_scan(in_deg)          (ONE single-WG kernel, fused in_norm)
//   fill: csr_src[row_start[dst[e]] + rank[e]] = src[e]  (no atomics)
//         + atomicAdd(&out_deg[src[e]], 1)
//   featp = fp16( rsqrt(out_deg) * (feat @ W1) )
//   s[n]  = rsqrt(out_deg[n]) * (relu(in_norm[n]*sum featp[src] + b1) . W2)
//           (one wave/node: 8 edge-groups x 8 chunks, unroll-2 -> 16 gathers in flight)
//   out[n] = sigmoid(in_norm[n]*sum s[src] + b2)  (16 lanes/node, unroll-2)

#define BS 256

__global__ void rank_kernel(const int* __restrict__ dst, int* __restrict__ in_cnt,
                            int* __restrict__ rank, int E) {
    int e = blockIdx.x * blockDim.x + threadIdx.x;
    if (e < E) {
        rank[e] = atomicAdd(&in_cnt[dst[e]], 1);
    }
}

// Single-workgroup exclusive scan of in_cnt (N=50k, L2-resident) + in_norm.
// Replaces the 3-kernel scan: thread-chunk serial sums -> block scan -> writeout.
__global__ __launch_bounds__(1024) void scan_all_kernel(const int* __restrict__ in_cnt,
                                                        int* __restrict__ row_start,
                                                        float* __restrict__ in_norm, int N) {
    __shared__ int ssum[1024];
    int t = threadIdx.x;
    int C = (N + 1023) / 1024;      // chunk size (49 for N=50000)
    int lo = t * C;
    int hi = lo + C; if (hi > N) hi = N;
    int s = 0;
    for (int i = lo; i < hi; i++) s += in_cnt[i];
    ssum[t] = s;
    __syncthreads();
    for (int off = 1; off < 1024; off <<= 1) {   // Hillis-Steele inclusive
        int v = (t >= off) ? ssum[t - off] : 0;
        __syncthreads();
        ssum[t] += v;
        __syncthreads();
    }
    int run = ssum[t] - s;          // exclusive prefix of this chunk
    for (int i = lo; i < hi; i++) {
        int d = in_cnt[i];
        row_start[i] = run;
        in_norm[i] = rsqrtf(fmaxf((float)d, 1.0f));
        run += d;
    }
}

// Atomic-free CSR scatter + out-degree count (no-return atomics).
__global__ void fill_csr_kernel(const int* __restrict__ src, const int* __restrict__ dst,
                                const int* __restrict__ rank, const int* __restrict__ row_start,
                                int* __restrict__ csr_src, int* __restrict__ out_deg, int E) {
    int e = blockIdx.x * blockDim.x + threadIdx.x;
    if (e < E) {
        int sn = src[e];
        csr_src[row_start[dst[e]] + rank[e]] = sn;
        atomicAdd(&out_deg[sn], 1);
    }
}

// featp = fp16(rsqrt(out_deg) * (feat @ W1)); one wave per row, lane = out column.
__global__ void featw1_kernel(const float* __restrict__ feat,
                              const float* __restrict__ W1,
                              const int* __restrict__ out_deg,
                              __half* __restrict__ featp, int N) {
    __shared__ float w[64 * 64];
    int tid = threadIdx.x;
    for (int i = tid; i < 64 * 16; i += blockDim.x)
        ((float4*)w)[i] = ((const float4*)W1)[i];
    __syncthreads();
    int wave = tid >> 6;
    int lane = tid & 63;
    int row = blockIdx.x * (blockDim.x >> 6) + wave;
    if (row >= N) return;
    const float4* fr = (const float4*)(feat + (size_t)row * 64);
    float acc = 0.0f;
    #pragma unroll
    for (int k4 = 0; k4 < 16; k4++) {
        float4 a = fr[k4];                        // wave-uniform broadcast
        acc += a.x * w[(4 * k4 + 0) * 64 + lane]; // lane stride-1: conflict-free
        acc += a.y * w[(4 * k4 + 1) * 64 + lane];
        acc += a.z * w[(4 * k4 + 2) * 64 + lane];
        acc += a.w * w[(4 * k4 + 3) * 64 + lane];
    }
    float onorm = rsqrtf(fmaxf((float)out_deg[row], 1.0f));
    featp[(size_t)row * 64 + lane] = __float2half(onorm * acc);
}

// Layer 1 fused: one wave/node. Lanes = 8 edge-groups (g) x 8 feature-chunks (l).
// Unroll-2: each lane issues TWO independent 16B gathers -> 16 edges in flight/wave.
__global__ void csr_agg1_kernel(const int* __restrict__ row_start, const int* __restrict__ in_deg,
                                const int* __restrict__ csr_src,
                                const __half* __restrict__ featp,
                                const float* __restrict__ b1, const float* __restrict__ W2,
                                const float* __restrict__ in_norm, const int* __restrict__ out_deg,
                                float* __restrict__ s_buf, int N) {
    int gid = blockIdx.x * blockDim.x + threadIdx.x;
    int n = gid >> 6;
    if (n >= N) return;
    int lane = threadIdx.x & 63;
    int g = lane >> 3;   // edge slot within batch of 8
    int l = lane & 7;    // feature chunk: features [8l, 8l+8)
    int start = row_start[n];
    int deg = in_deg[n];
    float acc[8] = {0, 0, 0, 0, 0, 0, 0, 0};
    const uint4* fp4 = (const uint4*)featp;      // 8 x uint4 per node (64 fp16)
    for (int j = 0; j < deg; j += 16) {
        int e0 = j + g;
        int e1 = j + 8 + g;
        bool p0 = e0 < deg;
        bool p1 = e1 < deg;
        int sn0 = p0 ? csr_src[start + e0] : 0;
        int sn1 = p1 ? csr_src[start + e1] : 0;
        uint4 q0 = {0, 0, 0, 0}, q1 = {0, 0, 0, 0};
        if (p0) q0 = fp4[(size_t)sn0 * 8 + l];   // two independent 16B gathers
        if (p1) q1 = fp4[(size_t)sn1 * 8 + l];
        const __half2* h0 = (const __half2*)&q0;
        const __half2* h1 = (const __half2*)&q1;
        #pragma unroll
        for (int c = 0; c < 4; c++) {
            if (p0) {
                float2 f = __half22float2(h0[c]);
                acc[2 * c]     += f.x;
                acc[2 * c + 1] += f.y;
            }
            if (p1) {
                float2 f = __half22float2(h1[c]);
                acc[2 * c]     += f.x;
                acc[2 * c + 1] += f.y;
            }
        }
    }
    // sum the 8 edge-groups (lanes differing in bits 3..5)
    #pragma unroll
    for (int off = 8; off < 64; off <<= 1) {
        #pragma unroll
        for (int c = 0; c < 8; c++)
            acc[c] += __shfl_xor(acc[c], off, 64);
    }
    // epilogue: h = relu(in_norm*acc + b1); v = h . W2 (chunk), then sum chunks
    float inn = in_norm[n];
    float v = 0.0f;
    #pragma unroll
    for (int c = 0; c < 8; c++) {
        float h = fmaxf(inn * acc[c] + b1[l * 8 + c], 0.0f);
        v += h * W2[l * 8 + c];
    }
    #pragma unroll
    for (int off = 1; off < 8; off <<= 1)
        v += __shfl_xor(v, off, 64);
    if (lane == 0) {
        float onorm = rsqrtf(fmaxf((float)out_deg[n], 1.0f));
        s_buf[n] = onorm * v;
    }
}

// Layer 2 fused: 16 lanes per node, unroll-2 (2 independent gathers in flight).
__global__ void csr_agg2_kernel(const int* __restrict__ row_start, const int* __restrict__ in_deg,
                                const int* __restrict__ csr_src,
                                const float* __restrict__ s_buf,
                                const float* __restrict__ in_norm, const float* __restrict__ b2,
                                float* __restrict__ out, int N) {
    int gid = blockIdx.x * blockDim.x + threadIdx.x;
    int n = gid >> 4;
    if (n >= N) return;
    int sub = gid & 15;
    int start = row_start[n];
    int deg = in_deg[n];
    float a = 0.0f;
    for (int j = sub; j < deg; j += 32) {
        int j1 = j + 16;
        int i0 = csr_src[start + j];
        int i1 = (j1 < deg) ? csr_src[start + j1] : 0;
        float v0 = s_buf[i0];
        float v1 = (j1 < deg) ? s_buf[i1] : 0.0f;
        a += v0 + v1;
    }
    #pragma unroll
    for (int off = 1; off < 16; off <<= 1)
        a += __shfl_xor(a, off, 64);
    if (sub == 0) {
        float x = in_norm[n] * a + b2[0];
        out[n] = 1.0f / (1.0f + expf(-x));
    }
}

extern "C" void kernel_launch(void* const* d_in, const int* in_sizes, int n_in,
                              void* d_out, int out_size, void* d_ws, size_t ws_size,
                              hipStream_t stream) {
    const float* feat = (const float*)d_in[0];
    const float* W1   = (const float*)d_in[1];
    const float* b1   = (const float*)d_in[2];
    const float* W2   = (const float*)d_in[3];
    const float* b2   = (const float*)d_in[4];
    const int* src = (const int*)d_in[5];
    const int* dst = (const int*)d_in[6];
    float* out = (float*)d_out;

    const int N = in_sizes[0] / 64;   // 50000
    const int E = in_sizes[5];        // 800000

    // workspace layout: int region | fp16 featp (16B-aligned) | float region
    char* wsb = (char*)d_ws;
    int* out_deg   = (int*)wsb;                      // N  (zeroed)
    int* in_cnt    = out_deg + N;                    // N  (zeroed; becomes in_deg)
    int* row_start = in_cnt + N;                     // N
    int* rank      = row_start + N;                  // E
    int* csr_src   = rank + E;                       // E
    size_t int_bytes = ((size_t)3 * N + 2 * (size_t)E) * sizeof(int);
    size_t half_off = (int_bytes + 15) & ~(size_t)15;
    __half* featp = (__half*)(wsb + half_off);       // 64N fp16 (16B-aligned)
    float* fbase  = (float*)(wsb + half_off + (size_t)64 * N * sizeof(__half));
    float* in_norm = fbase;                          // N
    float* s_buf   = fbase + (size_t)N;              // N

    hipMemsetAsync(wsb, 0, (size_t)2 * N * sizeof(int), stream);

    rank_kernel<<<(E + BS - 1) / BS, BS, 0, stream>>>(dst, in_cnt, rank, E);
    scan_all_kernel<<<1, 1024, 0, stream>>>(in_cnt, row_start, in_norm, N);
    fill_csr_kernel<<<(E + BS - 1) / BS, BS, 0, stream>>>(src, dst, rank, row_start, csr_src, out_deg, E);
    featw1_kernel<<<(N + 3) / 4, BS, 0, stream>>>(feat, W1, out_deg, featp, N);
    csr_agg1_kernel<<<(int)(((size_t)N * 64 + BS - 1) / BS), BS, 0, stream>>>(
        row_start, in_cnt, csr_src, featp, b1, W2, in_norm, out_deg, s_buf, N);
    csr_agg2_kernel<<<(int)(((size_t)N * 16 + BS - 1) / BS), BS, 0, stream>>>(
        row_start, in_cnt, csr_src, s_buf, in_norm, b2, out, N);
}

// Round 8
// 227.143 us; speedup vs baseline: 1.4291x; 1.4291x over previous
//
#include <hip/hip_runtime.h>
#include <hip/hip_fp16.h>
#include <math.h>

// GCN 2-layer (DGL GraphConv norm='both'), CSR via rank-atomics:
//   rank[e] = atomicAdd(&in_cnt[dst[e]], 1)    -> in_cnt becomes in_deg
//   row_start = exclusive_scan(in_deg)          (3-kernel multi-CU scan; round-7's
//                                                single-WG scan was a 113us latency trap)
//   fill: csr_src[row_start[dst[e]] + rank[e]] = src[e]  (no atomics)
//         + atomicAdd(&out_deg[src[e]], 1)
//   featp = fp16( rsqrt(out_deg) * (feat @ W1) )
//   s[n]  = rsqrt(out_deg[n]) * (relu(in_norm[n]*sum featp[src] + b1) . W2)
//           (one wave/node: 8 edge-groups x 8 chunks, unroll-2 -> 16 gathers in flight)
//   out[n] = sigmoid(in_norm[n]*sum s[src] + b2)  (16 lanes/node, unroll-2)

#define BS 256

__global__ void rank_kernel(const int* __restrict__ dst, int* __restrict__ in_cnt,
                            int* __restrict__ rank, int E) {
    int e = blockIdx.x * blockDim.x + threadIdx.x;
    if (e < E) {
        rank[e] = atomicAdd(&in_cnt[dst[e]], 1);
    }
}

__global__ void block_sum_kernel(const int* __restrict__ deg, int* __restrict__ bsum, int N) {
    __shared__ int s[BS];
    int i = blockIdx.x * BS + threadIdx.x;
    s[threadIdx.x] = (i < N) ? deg[i] : 0;
    __syncthreads();
    for (int off = BS / 2; off > 0; off >>= 1) {
        if (threadIdx.x < off) s[threadIdx.x] += s[threadIdx.x + off];
        __syncthreads();
    }
    if (threadIdx.x == 0) bsum[blockIdx.x] = s[0];
}

__global__ void scan_bsum_kernel(const int* __restrict__ bsum, int* __restrict__ boff, int nb) {
    __shared__ int s[512];
    int t = threadIdx.x;
    for (int i = t; i < nb; i += blockDim.x) s[i] = bsum[i];
    __syncthreads();
    if (t == 0) {
        int acc = 0;
        for (int i = 0; i < nb; i++) { int v = s[i]; s[i] = acc; acc += v; }
    }
    __syncthreads();
    for (int i = t; i < nb; i += blockDim.x) boff[i] = s[i];
}

// exclusive scan finalize + in_norm (out_norm folded into consumers)
__global__ void scan_final_kernel(const int* __restrict__ in_deg, const int* __restrict__ boff,
                                  int* __restrict__ row_start, float* __restrict__ in_norm, int N) {
    __shared__ int s[BS];
    int i = blockIdx.x * BS + threadIdx.x;
    int v = (i < N) ? in_deg[i] : 0;
    s[threadIdx.x] = v;
    __syncthreads();
    for (int off = 1; off < BS; off <<= 1) {
        int t = (threadIdx.x >= off) ? s[threadIdx.x - off] : 0;
        __syncthreads();
        s[threadIdx.x] += t;
        __syncthreads();
    }
    if (i < N) {
        row_start[i] = boff[blockIdx.x] + s[threadIdx.x] - v;  // exclusive
        in_norm[i]   = rsqrtf(fmaxf((float)v, 1.0f));
    }
}

// Atomic-free CSR scatter + out-degree count (no-return atomics).
__global__ void fill_csr_kernel(const int* __restrict__ src, const int* __restrict__ dst,
                                const int* __restrict__ rank, const int* __restrict__ row_start,
                                int* __restrict__ csr_src, int* __restrict__ out_deg, int E) {
    int e = blockIdx.x * blockDim.x + threadIdx.x;
    if (e < E) {
        int sn = src[e];
        csr_src[row_start[dst[e]] + rank[e]] = sn;
        atomicAdd(&out_deg[sn], 1);
    }
}

// featp = fp16(rsqrt(out_deg) * (feat @ W1)); one wave per row, lane = out column.
__global__ void featw1_kernel(const float* __restrict__ feat,
                              const float* __restrict__ W1,
                              const int* __restrict__ out_deg,
                              __half* __restrict__ featp, int N) {
    __shared__ float w[64 * 64];
    int tid = threadIdx.x;
    for (int i = tid; i < 64 * 16; i += blockDim.x)
        ((float4*)w)[i] = ((const float4*)W1)[i];
    __syncthreads();
    int wave = tid >> 6;
    int lane = tid & 63;
    int row = blockIdx.x * (blockDim.x >> 6) + wave;
    if (row >= N) return;
    const float4* fr = (const float4*)(feat + (size_t)row * 64);
    float acc = 0.0f;
    #pragma unroll
    for (int k4 = 0; k4 < 16; k4++) {
        float4 a = fr[k4];                        // wave-uniform broadcast
        acc += a.x * w[(4 * k4 + 0) * 64 + lane]; // lane stride-1: conflict-free
        acc += a.y * w[(4 * k4 + 1) * 64 + lane];
        acc += a.z * w[(4 * k4 + 2) * 64 + lane];
        acc += a.w * w[(4 * k4 + 3) * 64 + lane];
    }
    float onorm = rsqrtf(fmaxf((float)out_deg[row], 1.0f));
    featp[(size_t)row * 64 + lane] = __float2half(onorm * acc);
}

// Layer 1 fused: one wave/node. Lanes = 8 edge-groups (g) x 8 feature-chunks (l).
// Unroll-2: each lane issues TWO independent 16B gathers -> 16 edges in flight/wave.
__global__ void csr_agg1_kernel(const int* __restrict__ row_start, const int* __restrict__ in_deg,
                                const int* __restrict__ csr_src,
                                const __half* __restrict__ featp,
                                const float* __restrict__ b1, const float* __restrict__ W2,
                                const float* __restrict__ in_norm, const int* __restrict__ out_deg,
                                float* __restrict__ s_buf, int N) {
    int gid = blockIdx.x * blockDim.x + threadIdx.x;
    int n = gid >> 6;
    if (n >= N) return;
    int lane = threadIdx.x & 63;
    int g = lane >> 3;   // edge slot within batch of 8
    int l = lane & 7;    // feature chunk: features [8l, 8l+8)
    int start = row_start[n];
    int deg = in_deg[n];
    float acc[8] = {0, 0, 0, 0, 0, 0, 0, 0};
    const uint4* fp4 = (const uint4*)featp;      // 8 x uint4 per node (64 fp16)
    for (int j = 0; j < deg; j += 16) {
        int e0 = j + g;
        int e1 = j + 8 + g;
        bool p0 = e0 < deg;
        bool p1 = e1 < deg;
        int sn0 = p0 ? csr_src[start + e0] : 0;
        int sn1 = p1 ? csr_src[start + e1] : 0;
        uint4 q0 = {0, 0, 0, 0}, q1 = {0, 0, 0, 0};
        if (p0) q0 = fp4[(size_t)sn0 * 8 + l];   // two independent 16B gathers
        if (p1) q1 = fp4[(size_t)sn1 * 8 + l];
        const __half2* h0 = (const __half2*)&q0;
        const __half2* h1 = (const __half2*)&q1;
        #pragma unroll
        for (int c = 0; c < 4; c++) {
            if (p0) {
                float2 f = __half22float2(h0[c]);
                acc[2 * c]     += f.x;
                acc[2 * c + 1] += f.y;
            }
            if (p1) {
                float2 f = __half22float2(h1[c]);
                acc[2 * c]     += f.x;
                acc[2 * c + 1] += f.y;
            }
        }
    }
    // sum the 8 edge-groups (lanes differing in bits 3..5)
    #pragma unroll
    for (int off = 8; off < 64; off <<= 1) {
        #pragma unroll
        for (int c = 0; c < 8; c++)
            acc[c] += __shfl_xor(acc[c], off, 64);
    }
    // epilogue: h = relu(in_norm*acc + b1); v = h . W2 (chunk), then sum chunks
    float inn = in_norm[n];
    float v = 0.0f;
    #pragma unroll
    for (int c = 0; c < 8; c++) {
        float h = fmaxf(inn * acc[c] + b1[l * 8 + c], 0.0f);
        v += h * W2[l * 8 + c];
    }
    #pragma unroll
    for (int off = 1; off < 8; off <<= 1)
        v += __shfl_xor(v, off, 64);
    if (lane == 0) {
        float onorm = rsqrtf(fmaxf((float)out_deg[n], 1.0f));
        s_buf[n] = onorm * v;
    }
}

// Layer 2 fused: 16 lanes per node, unroll-2 (2 independent gathers in flight).
__global__ void csr_agg2_kernel(const int* __restrict__ row_start, const int* __restrict__ in_deg,
                                const int* __restrict__ csr_src,
                                const float* __restrict__ s_buf,
                                const float* __restrict__ in_norm, const float* __restrict__ b2,
                                float* __restrict__ out, int N) {
    int gid = blockIdx.x * blockDim.x + threadIdx.x;
    int n = gid >> 4;
    if (n >= N) return;
    int sub = gid & 15;
    int start = row_start[n];
    int deg = in_deg[n];
    float a = 0.0f;
    for (int j = sub; j < deg; j += 32) {
        int j1 = j + 16;
        int i0 = csr_src[start + j];
        int i1 = (j1 < deg) ? csr_src[start + j1] : 0;
        float v0 = s_buf[i0];
        float v1 = (j1 < deg) ? s_buf[i1] : 0.0f;
        a += v0 + v1;
    }
    #pragma unroll
    for (int off = 1; off < 16; off <<= 1)
        a += __shfl_xor(a, off, 64);
    if (sub == 0) {
        float x = in_norm[n] * a + b2[0];
        out[n] = 1.0f / (1.0f + expf(-x));
    }
}

extern "C" void kernel_launch(void* const* d_in, const int* in_sizes, int n_in,
                              void* d_out, int out_size, void* d_ws, size_t ws_size,
                              hipStream_t stream) {
    const float* feat = (const float*)d_in[0];
    const float* W1   = (const float*)d_in[1];
    const float* b1   = (const float*)d_in[2];
    const float* W2   = (const float*)d_in[3];
    const float* b2   = (const float*)d_in[4];
    const int* src = (const int*)d_in[5];
    const int* dst = (const int*)d_in[6];
    float* out = (float*)d_out;

    const int N = in_sizes[0] / 64;   // 50000
    const int E = in_sizes[5];        // 800000
    const int nb = (N + BS - 1) / BS; // scan blocks

    // workspace layout: int region | fp16 featp (16B-aligned) | float region
    char* wsb = (char*)d_ws;
    int* out_deg   = (int*)wsb;                      // N  (zeroed)
    int* in_cnt    = out_deg + N;                    // N  (zeroed; becomes in_deg)
    int* row_start = in_cnt + N;                     // N
    int* bsum      = row_start + N;                  // nb
    int* boff      = bsum + nb;                      // nb
    int* rank      = boff + nb;                      // E
    int* csr_src   = rank + E;                       // E
    size_t int_bytes = ((size_t)3 * N + 2 * nb + 2 * (size_t)E) * sizeof(int);
    size_t half_off = (int_bytes + 15) & ~(size_t)15;
    __half* featp = (__half*)(wsb + half_off);       // 64N fp16 (16B-aligned)
    float* fbase  = (float*)(wsb + half_off + (size_t)64 * N * sizeof(__half));
    float* in_norm = fbase;                          // N
    float* s_buf   = fbase + (size_t)N;              // N

    hipMemsetAsync(wsb, 0, (size_t)2 * N * sizeof(int), stream);

    rank_kernel<<<(E + BS - 1) / BS, BS, 0, stream>>>(dst, in_cnt, rank, E);
    block_sum_kernel<<<nb, BS, 0, stream>>>(in_cnt, bsum, N);
    scan_bsum_kernel<<<1, 512, 0, stream>>>(bsum, boff, nb);
    scan_final_kernel<<<nb, BS, 0, stream>>>(in_cnt, boff, row_start, in_norm, N);
    fill_csr_kernel<<<(E + BS - 1) / BS, BS, 0, stream>>>(src, dst, rank, row_start, csr_src, out_deg, E);
    featw1_kernel<<<(N + 3) / 4, BS, 0, stream>>>(feat, W1, out_deg, featp, N);
    csr_agg1_kernel<<<(int)(((size_t)N * 64 + BS - 1) / BS), BS, 0, stream>>>(
        row_start, in_cnt, csr_src, featp, b1, W2, in_norm, out_deg, s_buf, N);
    csr_agg2_kernel<<<(int)(((size_t)N * 16 + BS - 1) / BS), BS, 0, stream>>>(
        row_start, in_cnt, csr_src, s_buf, in_norm, b2, out, N);
}

// Round 9
// 185.553 us; speedup vs baseline: 1.7494x; 1.2241x over previous
//
#include <hip/hip_runtime.h>
#include <hip/hip_fp16.h>
#include <math.h>

// GCN 2-layer (DGL GraphConv norm='both'). CSR built by a two-level MSD
// counting sort with NO per-edge global atomics (round-8 evidence: the two
// 800k-global-atomic passes were ~165us of the 227us total at ~25G atomics/s).
//   A : per-block LDS hist of dst>>8 and src>>8 (+38k tiny global adds)
//       fused with featw1 = fp16(feat @ W1), UNNORMALIZED (out_norm moves to agg1)
//   C0: 1-block exclusive scan of the 196 bin counts -> bases + cursors
//   B : partition: edges scattered by dst-high (packed src|dstLow<<17, LDS ranks,
//       per-block range reserve), src-low bytes scattered by src-high
//   D : per 256-node bin: LDS hist of low byte -> in_deg, row_start, csr_src
//       scatter; src bins -> out_deg (written directly, no zeroing needed)
//   agg1: one wave/node, 8 edge-groups x 8 fp16 chunks, unroll-2; applies
//         rsqrt(out_deg[src]) per edge, relu+b1+.W2 epilogue -> s_buf
//   agg2: 16 lanes/node -> sigmoid -> out
// Requires N <= 65536 (src packed into 17 bits, NB <= 256). N=50000 here.

#define BS 256
#define EPB 4096   // edges per partition block (16 iters of 256)

// ---- A: bin histograms + featw1 (independent work co-scheduled) ----
__global__ void histA_featw1_kernel(const int* __restrict__ src, const int* __restrict__ dst,
                                    const float* __restrict__ feat, const float* __restrict__ W1,
                                    int* __restrict__ dstBinCount, int* __restrict__ srcBinCount,
                                    __half* __restrict__ featp,
                                    int E, int N, int NB, int T) {
    __shared__ float w[64 * 64];
    __shared__ int histD[256];
    __shared__ int histS[256];
    int tid = threadIdx.x;
    if ((int)blockIdx.x < T) {
        histD[tid] = 0; histS[tid] = 0;
        __syncthreads();
        int base = blockIdx.x * EPB;
        #pragma unroll
        for (int it = 0; it < EPB / BS; it++) {
            int e = base + it * BS + tid;
            if (e < E) {
                atomicAdd(&histD[dst[e] >> 8], 1);
                atomicAdd(&histS[src[e] >> 8], 1);
            }
        }
        __syncthreads();
        if (tid < NB) {
            if (histD[tid]) atomicAdd(&dstBinCount[tid], histD[tid]);
            if (histS[tid]) atomicAdd(&srcBinCount[tid], histS[tid]);
        }
    } else {
        for (int i = tid; i < 64 * 16; i += BS)
            ((float4*)w)[i] = ((const float4*)W1)[i];
        __syncthreads();
        int wave = tid >> 6, lane = tid & 63;
        int row = ((int)blockIdx.x - T) * 4 + wave;
        if (row >= N) return;
        const float4* fr = (const float4*)(feat + (size_t)row * 64);
        float acc = 0.0f;
        #pragma unroll
        for (int k4 = 0; k4 < 16; k4++) {
            float4 a = fr[k4];                         // wave-uniform broadcast
            acc += a.x * w[(4 * k4 + 0) * 64 + lane];  // lane stride-1: conflict-free
            acc += a.y * w[(4 * k4 + 1) * 64 + lane];
            acc += a.z * w[(4 * k4 + 2) * 64 + lane];
            acc += a.w * w[(4 * k4 + 3) * 64 + lane];
        }
        featp[(size_t)row * 64 + lane] = __float2half(acc);   // UNNORMALIZED
    }
}

// ---- C0: scan both 196-bin count arrays (tiny, 1 block) ----
__global__ void scan_bins_kernel(const int* __restrict__ dstBinCount, const int* __restrict__ srcBinCount,
                                 int* __restrict__ dstBinBase, int* __restrict__ srcBinBase,
                                 int* __restrict__ dstCursor, int* __restrict__ srcCursor, int NB) {
    __shared__ int s[256];
    int t = threadIdx.x;
    int v = (t < NB) ? dstBinCount[t] : 0;
    s[t] = v; __syncthreads();
    for (int off = 1; off < 256; off <<= 1) {
        int u = (t >= off) ? s[t - off] : 0; __syncthreads();
        s[t] += u; __syncthreads();
    }
    if (t < NB) {
        int ex = s[t] - v;
        dstBinBase[t] = ex; dstCursor[t] = ex;
        if (t == NB - 1) dstBinBase[NB] = s[t];
    }
    __syncthreads();
    v = (t < NB) ? srcBinCount[t] : 0;
    s[t] = v; __syncthreads();
    for (int off = 1; off < 256; off <<= 1) {
        int u = (t >= off) ? s[t - off] : 0; __syncthreads();
        s[t] += u; __syncthreads();
    }
    if (t < NB) {
        int ex = s[t] - v;
        srcBinBase[t] = ex; srcCursor[t] = ex;
        if (t == NB - 1) srcBinBase[NB] = s[t];
    }
}

// ---- B: partition edges by dst>>8 and src-lows by src>>8 (LDS ranks) ----
__global__ void partition_kernel(const int* __restrict__ src, const int* __restrict__ dst,
                                 int* __restrict__ dstCursor, int* __restrict__ srcCursor,
                                 int* __restrict__ packed, int* __restrict__ srcPart,
                                 int E, int NB) {
    __shared__ int arr[256];
    int tid = threadIdx.x;
    int base = blockIdx.x * EPB;
    // dst partition
    arr[tid] = 0; __syncthreads();
    #pragma unroll
    for (int it = 0; it < EPB / BS; it++) {
        int e = base + it * BS + tid;
        if (e < E) atomicAdd(&arr[dst[e] >> 8], 1);
    }
    __syncthreads();
    int h = arr[tid];
    int rb = (tid < NB && h) ? atomicAdd(&dstCursor[tid], h) : 0;
    __syncthreads();
    arr[tid] = rb;
    __syncthreads();
    #pragma unroll
    for (int it = 0; it < EPB / BS; it++) {
        int e = base + it * BS + tid;
        if (e < E) {
            int d = dst[e], s2 = src[e];
            int pos = atomicAdd(&arr[d >> 8], 1);
            packed[pos] = s2 | ((d & 255) << 17);
        }
    }
    __syncthreads();
    // src partition (for out_deg counting)
    arr[tid] = 0; __syncthreads();
    #pragma unroll
    for (int it = 0; it < EPB / BS; it++) {
        int e = base + it * BS + tid;
        if (e < E) atomicAdd(&arr[src[e] >> 8], 1);
    }
    __syncthreads();
    h = arr[tid];
    rb = (tid < NB && h) ? atomicAdd(&srcCursor[tid], h) : 0;
    __syncthreads();
    arr[tid] = rb;
    __syncthreads();
    #pragma unroll
    for (int it = 0; it < EPB / BS; it++) {
        int e = base + it * BS + tid;
        if (e < E) {
            int s2 = src[e];
            int pos = atomicAdd(&arr[s2 >> 8], 1);
            srcPart[pos] = s2 & 255;
        }
    }
}

// ---- D: per-bin finalize: in_deg/row_start/csr_src (dst bins), out_deg (src bins) ----
__global__ void finalize_kernel(const int* __restrict__ dstBinBase, const int* __restrict__ srcBinBase,
                                const int* __restrict__ packed, const int* __restrict__ srcPart,
                                int* __restrict__ csr_src, int* __restrict__ in_deg,
                                int* __restrict__ row_start, int* __restrict__ out_deg,
                                int N, int NB) {
    __shared__ int hist[256];
    __shared__ int sc[256];
    int tid = threadIdx.x;
    int b = blockIdx.x;
    if (b < NB) {
        int lo = dstBinBase[b], hi = dstBinBase[b + 1];
        hist[tid] = 0; __syncthreads();
        for (int i = lo + tid; i < hi; i += BS)
            atomicAdd(&hist[(packed[i] >> 17) & 255], 1);
        __syncthreads();
        int v = hist[tid];
        sc[tid] = v; __syncthreads();
        for (int off = 1; off < 256; off <<= 1) {
            int u = (tid >= off) ? sc[tid - off] : 0; __syncthreads();
            sc[tid] += u; __syncthreads();
        }
        int ex = sc[tid] - v;          // exclusive within bin
        int n = b * 256 + tid;
        if (n < N) { in_deg[n] = v; row_start[n] = lo + ex; }
        sc[tid] = lo + ex;             // becomes the scatter cursor
        __syncthreads();
        for (int i = lo + tid; i < hi; i += BS) {
            int pv = packed[i];
            int pos = atomicAdd(&sc[(pv >> 17) & 255], 1);
            csr_src[pos] = pv & 0x1FFFF;
        }
    } else {
        int sb = b - NB;
        int lo = srcBinBase[sb], hi = srcBinBase[sb + 1];
        hist[tid] = 0; __syncthreads();
        for (int i = lo + tid; i < hi; i += BS)
            atomicAdd(&hist[srcPart[i]], 1);
        __syncthreads();
        int n = sb * 256 + tid;
        if (n < N) out_deg[n] = hist[tid];
    }
}

// ---- agg1: one wave/node; 8 edge-groups x 8 chunks, unroll-2; on-the-fly norms ----
__global__ void csr_agg1_kernel(const int* __restrict__ row_start, const int* __restrict__ in_deg,
                                const int* __restrict__ csr_src, const int* __restrict__ out_deg,
                                const __half* __restrict__ featp,
                                const float* __restrict__ b1, const float* __restrict__ W2,
                                float* __restrict__ s_buf, int N) {
    int gid = blockIdx.x * blockDim.x + threadIdx.x;
    int n = gid >> 6;
    if (n >= N) return;
    int lane = threadIdx.x & 63;
    int g = lane >> 3;   // edge slot within batch of 8
    int l = lane & 7;    // feature chunk: features [8l, 8l+8)
    int start = row_start[n];
    int deg = in_deg[n];
    float acc[8] = {0, 0, 0, 0, 0, 0, 0, 0};
    const uint4* fp4 = (const uint4*)featp;
    for (int j = 0; j < deg; j += 16) {
        int e0 = j + g;
        int e1 = j + 8 + g;
        bool p0 = e0 < deg;
        bool p1 = e1 < deg;
        int sn0 = p0 ? csr_src[start + e0] : 0;
        int sn1 = p1 ? csr_src[start + e1] : 0;
        uint4 q0 = {0, 0, 0, 0}, q1 = {0, 0, 0, 0};
        float on0 = 0.0f, on1 = 0.0f;
        if (p0) { q0 = fp4[(size_t)sn0 * 8 + l]; on0 = rsqrtf(fmaxf((float)out_deg[sn0], 1.0f)); }
        if (p1) { q1 = fp4[(size_t)sn1 * 8 + l]; on1 = rsqrtf(fmaxf((float)out_deg[sn1], 1.0f)); }
        const __half2* h0 = (const __half2*)&q0;
        const __half2* h1 = (const __half2*)&q1;
        #pragma unroll
        for (int c = 0; c < 4; c++) {
            float2 f0 = __half22float2(h0[c]);
            float2 f1 = __half22float2(h1[c]);
            acc[2 * c]     += on0 * f0.x + on1 * f1.x;
            acc[2 * c + 1] += on0 * f0.y + on1 * f1.y;
        }
    }
    #pragma unroll
    for (int off = 8; off < 64; off <<= 1) {
        #pragma unroll
        for (int c = 0; c < 8; c++)
            acc[c] += __shfl_xor(acc[c], off, 64);
    }
    float inn = rsqrtf(fmaxf((float)deg, 1.0f));
    float v = 0.0f;
    #pragma unroll
    for (int c = 0; c < 8; c++) {
        float h = fmaxf(inn * acc[c] + b1[l * 8 + c], 0.0f);
        v += h * W2[l * 8 + c];
    }
    #pragma unroll
    for (int off = 1; off < 8; off <<= 1)
        v += __shfl_xor(v, off, 64);
    if (lane == 0)
        s_buf[n] = rsqrtf(fmaxf((float)out_deg[n], 1.0f)) * v;
}

// ---- agg2: 16 lanes/node, unroll-2, sigmoid -> out ----
__global__ void csr_agg2_kernel(const int* __restrict__ row_start, const int* __restrict__ in_deg,
                                const int* __restrict__ csr_src,
                                const float* __restrict__ s_buf, const float* __restrict__ b2,
                                float* __restrict__ out, int N) {
    int gid = blockIdx.x * blockDim.x + threadIdx.x;
    int n = gid >> 4;
    if (n >= N) return;
    int sub = gid & 15;
    int start = row_start[n];
    int deg = in_deg[n];
    float a = 0.0f;
    for (int j = sub; j < deg; j += 32) {
        int j1 = j + 16;
        int i0 = csr_src[start + j];
        int i1 = (j1 < deg) ? csr_src[start + j1] : 0;
        float v0 = s_buf[i0];
        float v1 = (j1 < deg) ? s_buf[i1] : 0.0f;
        a += v0 + v1;
    }
    #pragma unroll
    for (int off = 1; off < 16; off <<= 1)
        a += __shfl_xor(a, off, 64);
    if (sub == 0) {
        float x = rsqrtf(fmaxf((float)deg, 1.0f)) * a + b2[0];
        out[n] = 1.0f / (1.0f + expf(-x));
    }
}

extern "C" void kernel_launch(void* const* d_in, const int* in_sizes, int n_in,
                              void* d_out, int out_size, void* d_ws, size_t ws_size,
                              hipStream_t stream) {
    const float* feat = (const float*)d_in[0];
    const float* W1   = (const float*)d_in[1];
    const float* b1   = (const float*)d_in[2];
    const float* W2   = (const float*)d_in[3];
    const float* b2   = (const float*)d_in[4];
    const int* src = (const int*)d_in[5];
    const int* dst = (const int*)d_in[6];
    float* out = (float*)d_out;

    const int N  = in_sizes[0] / 64;       // 50000
    const int E  = in_sizes[5];            // 800000
    const int NB = (N + 255) >> 8;         // 196 bins of 256 nodes
    const int T  = (E + EPB - 1) / EPB;    // 196 partition blocks

    // workspace: int region | fp16 featp (16B-aligned) | float s_buf
    int* wsi = (int*)d_ws;
    int* dstBinCount = wsi;                          // NB  (zeroed together)
    int* srcBinCount = dstBinCount + NB;             // NB
    int* dstBinBase  = srcBinCount + NB;             // NB+1
    int* srcBinBase  = dstBinBase + NB + 1;          // NB+1
    int* dstCursor   = srcBinBase + NB + 1;          // NB
    int* srcCursor   = dstCursor + NB;               // NB
    int* in_deg      = srcCursor + NB;               // N
    int* row_start   = in_deg + N;                   // N
    int* out_deg     = row_start + N;                // N
    int* packed      = out_deg + N;                  // E
    int* srcPart     = packed + E;                   // E
    int* csr_src     = srcPart + E;                  // E
    size_t int_bytes = ((size_t)(6 * NB + 2) + 3 * (size_t)N + 3 * (size_t)E) * sizeof(int);
    size_t half_off  = (int_bytes + 15) & ~(size_t)15;
    __half* featp = (__half*)((char*)d_ws + half_off);            // 64N fp16
    float* s_buf  = (float*)((char*)d_ws + half_off + (size_t)64 * N * sizeof(__half));

    hipMemsetAsync(dstBinCount, 0, (size_t)2 * NB * sizeof(int), stream);

    histA_featw1_kernel<<<T + (N + 3) / 4, BS, 0, stream>>>(
        src, dst, feat, W1, dstBinCount, srcBinCount, featp, E, N, NB, T);
    scan_bins_kernel<<<1, 256, 0, stream>>>(
        dstBinCount, srcBinCount, dstBinBase, srcBinBase, dstCursor, srcCursor, NB);
    partition_kernel<<<T, BS, 0, stream>>>(
        src, dst, dstCursor, srcCursor, packed, srcPart, E, NB);
    finalize_kernel<<<2 * NB, BS, 0, stream>>>(
        dstBinBase, srcBinBase, packed, srcPart, csr_src, in_deg, row_start, out_deg, N, NB);
    csr_agg1_kernel<<<(int)(((size_t)N * 64 + BS - 1) / BS), BS, 0, stream>>>(
        row_start, in_deg, csr_src, out_deg, featp, b1, W2, s_buf, N);
    csr_agg2_kernel<<<(int)(((size_t)N * 16 + BS - 1) / BS), BS, 0, stream>>>(
        row_start, in_deg, csr_src, s_buf, b2, out, N);
}